// Round 19
// baseline (286.454 us; speedup 1.0000x reference)
//
#include <hip/hip_runtime.h>
#include <hip/hip_bf16.h>

typedef __hip_bfloat16 bf16;
typedef __attribute__((ext_vector_type(8))) short short8v;
typedef __attribute__((ext_vector_type(4))) float f32x4;
typedef __attribute__((ext_vector_type(16))) float f32x16;

#define HH 270
#define WW 512
#define BB 4
#define HP 271
#define WP 513
#define NPIX (HH*WW)      // 138240
#define NPOOL (HP*WP)     // 139023
#define TWO_PI 6.28318530717958647692f
#define PLANE ((size_t)BB*NPIX*16)   // shorts per 16-ch f2 plane
#define NBLK_BILAT ((BB*NPIX)/256)   // 2160, exact

// ---------------------------------------------------------------------------
// Weight prep + zero-page init.
//  - apack: conv1 weights bf16, mfma_f32_32x32x16_bf16 A-frag order,
//    K-tile = 16 in-ch:  [ck 8][tap 25][lane 64][j 8]
//  - a2pack: conv2 weights bf16, mfma_f32_16x16x32 A-frag: [tap 9][lane][8]
//  - a3pack: conv3 weights bf16, 4 taps packed per K=32: [grp 7][lane][8]
//  - zp: 4 KB zero page (OOB redirect target). Zeroed every launch.
__global__ void k_wprep(const float* __restrict__ w1, const float* __restrict__ w2,
                        const float* __restrict__ w3, short* __restrict__ apack,
                        short* __restrict__ a2pack, short* __restrict__ a3pack,
                        float* __restrict__ zp) {
    int stride = gridDim.x * blockDim.x;
    int t0 = blockIdx.x * blockDim.x + threadIdx.x;
    for (int i = t0; i < 1024; i += stride) zp[i] = 0.f;
    for (int i = t0; i < 8*25*64*8; i += stride) {
        int idx = i;
        int j    = idx & 7;  idx >>= 3;
        int lane = idx & 63; idx >>= 6;
        int t    = idx % 25;
        int ck   = idx / 25;
        int o = lane & 31;
        int c = ck*16 + (lane >> 5)*8 + j;
        float v = w1[o*3200 + c*25 + t];
        bf16 h = __float2bfloat16(v);
        apack[i] = *reinterpret_cast<short*>(&h);
    }
    for (int i = t0; i < 9*64*8; i += stride) {
        int j = i & 7; int l = (i >> 3) & 63; int tap = i >> 9;
        int o = l & 15; int cin = (l >> 4)*8 + j;
        float v = (o < 8) ? w2[o*288 + cin*9 + tap] : 0.f;
        bf16 h = __float2bfloat16(v);
        a2pack[i] = *reinterpret_cast<short*>(&h);
    }
    for (int i = t0; i < 7*64*8; i += stride) {
        int j = i & 7; int l = (i >> 3) & 63; int grp = i >> 9;
        int o = l & 15; int tap = grp*4 + (l >> 4);
        float v = (o < 2 && tap < 25) ? w3[o*200 + j*25 + tap] : 0.f;
        bf16 h = __float2bfloat16(v);
        a3pack[i] = *reinterpret_cast<short*>(&h);
    }
}

// ---------------------------------------------------------------------------
// Tiled pool: per-pixel grad/atan2/soft-bin ONCE into 8-ch LDS histogram,
// then 4x4 window sum per output pixel.
__global__ __launch_bounds__(256) void k_pool(const float* __restrict__ x,
                                              float* __restrict__ pooled) {
    __shared__ float hist[8][19][20];
    const int tx = threadIdx.x & 15, ty = threadIdx.x >> 4;
    const int j0 = blockIdx.x * 16, i0 = blockIdx.y * 16, b = blockIdx.z;
    const float* xb = x + (size_t)b * NPIX;

    for (int i = threadIdx.x; i < 8*19*20; i += 256) ((float*)hist)[i] = 0.f;
    __syncthreads();

    for (int i = threadIdx.x; i < 361; i += 256) {
        int lh = i / 19, lw = i - lh*19;
        int hh = i0 + lh - 2, ww = j0 + lw - 2;
        if (hh >= 0 && hh < HH && ww >= 0 && ww < WW) {
            float gx = xb[hh*WW + (ww+1 < WW ? ww+1 : WW-1)] - xb[hh*WW + (ww-1 >= 0 ? ww-1 : 0)];
            float gy = xb[(hh+1 < HH ? hh+1 : HH-1)*WW + ww] - xb[(hh-1 >= 0 ? hh-1 : 0)*WW + ww];
            float mag  = sqrtf(gx*gx + gy*gy + 1e-10f);
            float ori  = atan2f(gy, gx + 1e-10f) + TWO_PI;
            float obig = ori * (8.0f / TWO_PI);
            float b0f  = floorf(obig);
            float wo1  = obig - b0f;
            int ib0 = ((int)b0f) & 7;
            int ib1 = (ib0 + 1) & 7;
            hist[ib0][lh][lw] += (1.0f - wo1) * mag;
            hist[ib1][lh][lw] += wo1 * mag;
        }
    }
    __syncthreads();

    int i = i0 + ty, j = j0 + tx;
    if (i < HP && j < WP) {
        float a[8];
        #pragma unroll
        for (int c = 0; c < 8; ++c) a[c] = 0.f;
        #pragma unroll
        for (int di = 0; di < 4; ++di)
            #pragma unroll
            for (int dj = 0; dj < 4; ++dj) {
                #pragma unroll
                for (int c = 0; c < 8; ++c)
                    a[c] += hist[c][ty+di][tx+dj];
            }
        float* pb = pooled + (size_t)b*8*NPOOL + i*WP + j;
        const float s = 1.0f/16.0f;
        #pragma unroll
        for (int c = 0; c < 8; ++c) pb[c*NPOOL] = a[c]*s;
    }
}

// ---------------------------------------------------------------------------
// SIFT normalize, tiled, TWO-PASS (R19): pass 2 packs vclip=min(u*inv1,0.2)
// as bf16 pairs into registers; pass 3 is register-only (unpack, fma, sqrt,
// repack) — removes the third 128-LDS-read pass (-33% LDS issue). Output:
// 8 PLANES of 16 ch, f2[ck][b][h][w][16] bf16, 8 x 32 B bursts/px.
__global__ __launch_bounds__(256) void k_feat(const float* __restrict__ pooled,
                                              short* __restrict__ f2) {
    __shared__ float T[8][19][19];
    const int tx = threadIdx.x & 15, ty = threadIdx.x >> 4;
    const int w0 = blockIdx.x * 16, h0 = blockIdx.y * 16, b = blockIdx.z;
    const float* pb = pooled + (size_t)b*8*NPOOL;

    for (int i = threadIdx.x; i < 8*361; i += 256) {
        int c = i / 361; int r = i - c*361; int lh = r / 19, lw = r - lh*19;
        int ph = h0 + lh - 1, pw = w0 + lw - 1;
        float v = 0.f;
        if (ph >= 0 && ph < HP && pw >= 0 && pw < WP)
            v = pb[c*NPOOL + ph*WP + pw];
        T[c][lh][lw] = v;
    }
    __syncthreads();

    // Pass 1: sum of squares.
    float s2 = 0.f;
    #pragma unroll
    for (int c = 0; c < 8; ++c)
        #pragma unroll
        for (int i = 0; i < 4; ++i)
            #pragma unroll
            for (int j = 0; j < 4; ++j) {
                float u = T[c][ty+i][tx+j];
                s2 += u*u;
            }
    float inv1 = 1.0f / fmaxf(sqrtf(s2), 1e-12f);

    // Pass 2: clip, accumulate sv1/sv2, AND pack vclip bf16 into registers.
    int outv[64];
    float sv2 = 0.f, sv1 = 0.f;
    #pragma unroll
    for (int c = 0; c < 8; ++c)
        #pragma unroll
        for (int i = 0; i < 4; ++i)
            #pragma unroll
            for (int jj = 0; jj < 2; ++jj) {
                float u0 = T[c][ty+i][tx+jj*2];
                float u1 = T[c][ty+i][tx+jj*2+1];
                float v0 = fminf(u0*inv1, 0.2f);
                float v1 = fminf(u1*inv1, 0.2f);
                sv2 += v0*v0 + v1*v1;
                sv1 += v0 + v1;
                bf16 hb0 = __float2bfloat16(v0);
                bf16 hb1 = __float2bfloat16(v1);
                unsigned lo = *reinterpret_cast<unsigned short*>(&hb0);
                unsigned hi = *reinterpret_cast<unsigned short*>(&hb1);
                outv[c*8 + i*2 + jj] = (int)(lo | (hi << 16));
            }
    float inv2  = 1.0f / fmaxf(sqrtf(sv2), 1e-12f);
    float invl1 = 1.0f / fmaxf(sv1 * inv2, 1e-12f);
    float scale = inv2 * invl1;       // fo = sqrt(vclip*scale + 1e-10)

    // Pass 3: register-only finalize (no LDS reads).
    #pragma unroll
    for (int q = 0; q < 64; ++q) {
        unsigned pk = (unsigned)outv[q];
        unsigned u0 = (pk & 0xFFFFu) << 16;
        unsigned u1 = pk & 0xFFFF0000u;
        float v0 = *reinterpret_cast<float*>(&u0);
        float v1 = *reinterpret_cast<float*>(&u1);
        float fo0 = sqrtf(v0*scale + 1e-10f);
        float fo1 = sqrtf(v1*scale + 1e-10f);
        bf16 hb0 = __float2bfloat16(fo0);
        bf16 hb1 = __float2bfloat16(fo1);
        unsigned lo = *reinterpret_cast<unsigned short*>(&hb0);
        unsigned hi = *reinterpret_cast<unsigned short*>(&hb1);
        outv[q] = (int)(lo | (hi << 16));
    }

    int h = h0 + ty, w = w0 + tx;
    if (h < HH) {
        const size_t pix = (size_t)b*NPIX + h*WW + w;
        #pragma unroll
        for (int ck = 0; ck < 8; ++ck) {
            int4* fb = reinterpret_cast<int4*>(f2 + (size_t)ck*PLANE + pix*16);
            int4 v0, v1;
            v0.x = outv[ck*8+0]; v0.y = outv[ck*8+1]; v0.z = outv[ck*8+2]; v0.w = outv[ck*8+3];
            v1.x = outv[ck*8+4]; v1.y = outv[ck*8+5]; v1.z = outv[ck*8+6]; v1.w = outv[ck*8+7];
            fb[0] = v0; fb[1] = v1;
        }
    }
}

// ---------------------------------------------------------------------------
// conv1 v10 (best measured, 132 us): per-wave private double-buffered LDS
// staging, ZERO barriers, counted vmcnt(9). 2 blocks/CU. v11/v12/v13/v13b
// all failed to beat it — this decomposition's floor.
__global__ __launch_bounds__(256) void k_conv1(const short* __restrict__ f2,
        const short* __restrict__ apack, const float* __restrict__ bias,
        short* __restrict__ c1o, const short* __restrict__ zp16) {
    __shared__ short S[4][2][4608];   // per wave: 2 bufs x 9216 B
    const int tid = threadIdx.x;
    const int l   = tid & 63;
    const int wid = tid >> 6;
    const int n      = blockIdx.x;
    const int xcd    = n & 7;
    const int t_     = n >> 3;
    const int within = t_ & 7;
    const int g      = (t_ >> 3)*8 + xcd;
    const int b      = g / 34;
    const int ypair  = g - b*34;
    const int h0     = (ypair*2 + (within >> 2)) * 4;
    const int w0     = (within & 3) * 128;
    const int c32 = l & 31;
    const int ksel = l >> 5;
    const int gw0 = w0 + wid*32 - 2;

    short* Sw0 = &S[wid][0][0];
    short* Sw1 = &S[wid][1][0];

    f32x16 acc0 = {0.f};
    f32x16 acc1 = {0.f};
    f32x16 acc2 = {0.f};
    f32x16 acc3 = {0.f};

    auto STAGE = [&](int ck, short* dstbase) {
        const short* plane = f2 + (size_t)ck*PLANE;
        #pragma unroll
        for (int j = 0; j < 9; ++j) {
            int s  = j*64 + l;
            int pr = s / 72;
            int rem = s - pr*72;
            int px = rem >> 1;
            int half = rem & 1;
            int gh = h0 + pr - 2;
            int gw = gw0 + px;
            const short* src = ((unsigned)gh < (unsigned)HH && (unsigned)gw < (unsigned)WW)
                ? plane + (((size_t)b*HH + gh)*WW + gw)*16 + half*8
                : zp16;
            __builtin_amdgcn_global_load_lds(
                (const __attribute__((address_space(1))) void*)src,
                (__attribute__((address_space(3))) void*)(dstbase + j*512), 16, 0, 0);
        }
    };

    STAGE(0, Sw0);

    for (int ck = 0; ck < 8; ++ck) {
        short* cur = (ck & 1) ? Sw1 : Sw0;
        short* nxt = (ck & 1) ? Sw0 : Sw1;
        if (ck < 7) STAGE(ck + 1, nxt);
        asm volatile("s_waitcnt vmcnt(9)" ::: "memory");

        #pragma unroll
        for (int kx = 0; kx < 5; ++kx) {
            const int px = c32 + kx;
            const short* bp = cur + (size_t)px*16 + (size_t)ksel*8;
            short8v Bf[8];
            #pragma unroll
            for (int pr = 0; pr < 8; ++pr)
                Bf[pr] = *reinterpret_cast<const short8v*>(bp + pr*576);
            #pragma unroll
            for (int ky = 0; ky < 5; ++ky) {
                const short* ap = apack + ((size_t)(ck*25 + ky*5 + kx)*64 + l)*8;
                short8v A = *reinterpret_cast<const short8v*>(ap);
                acc0 = __builtin_amdgcn_mfma_f32_32x32x16_bf16(A, Bf[ky+0], acc0, 0, 0, 0);
                acc1 = __builtin_amdgcn_mfma_f32_32x32x16_bf16(A, Bf[ky+1], acc1, 0, 0, 0);
                acc2 = __builtin_amdgcn_mfma_f32_32x32x16_bf16(A, Bf[ky+2], acc2, 0, 0, 0);
                acc3 = __builtin_amdgcn_mfma_f32_32x32x16_bf16(A, Bf[ky+3], acc3, 0, 0, 0);
            }
        }
        asm volatile("s_waitcnt lgkmcnt(0)" ::: "memory");
    }

    const int px = w0 + wid*32 + c32;
    #pragma unroll
    for (int r = 0; r < 4; ++r) {
        int h = h0 + r;
        if (h < HH) {
            const f32x16& A = (r==0) ? acc0 : (r==1) ? acc1 : (r==2) ? acc2 : acc3;
            const size_t rowbase = ((size_t)b*HH + h)*4;
            #pragma unroll
            for (int q = 0; q < 4; ++q) {
                short4 pk;
                short* pkp = (short*)&pk;
                #pragma unroll
                for (int j = 0; j < 4; ++j) {
                    float v = fmaxf(A[q*4 + j] + bias[q*8 + 4*ksel + j], 0.f);
                    bf16 hb = __float2bfloat16(v);
                    pkp[j] = *reinterpret_cast<short*>(&hb);
                }
                *reinterpret_cast<short4*>(c1o + ((rowbase + q)*WW + px)*8 + ksel*4) = pk;
            }
        }
    }
}

// ---------------------------------------------------------------------------
// conv2m: 32->8 ch, 3x3, pad 1, ReLU via mfma_f32_16x16x32_bf16.
__global__ __launch_bounds__(256) void k_conv2m(const short* __restrict__ c1o,
        const short* __restrict__ a2pack, const float* __restrict__ bias,
        short* __restrict__ c2o, const short* __restrict__ zp16) {
    const int tid = threadIdx.x;
    const int l   = tid & 63;
    const int wid = tid >> 6;
    const int h   = blockIdx.y;
    const int b   = blockIdx.z;
    const int w0  = blockIdx.x*256 + wid*64;
    const int col = l & 15;
    const int kg  = l >> 4;           // k-group == c1o quad

    f32x4 acc0 = {0.f,0.f,0.f,0.f};
    f32x4 acc1 = {0.f,0.f,0.f,0.f};
    f32x4 acc2 = {0.f,0.f,0.f,0.f};
    f32x4 acc3 = {0.f,0.f,0.f,0.f};

    #pragma unroll
    for (int ky = 0; ky < 3; ++ky) {
        int gh = h + ky - 1;
        bool rv = ((unsigned)gh < (unsigned)HH);
        const short* rowb = c1o + (((size_t)b*HH + (rv ? gh : 0))*4 + kg)*WW*8;
        #pragma unroll
        for (int kx = 0; kx < 3; ++kx) {
            short8v A = *reinterpret_cast<const short8v*>(
                a2pack + ((size_t)(ky*3 + kx)*64 + l)*8);
            #pragma unroll
            for (int nt = 0; nt < 4; ++nt) {
                int gw = w0 + nt*16 + col + kx - 1;
                const short* src = (rv && (unsigned)gw < (unsigned)WW)
                    ? rowb + (size_t)gw*8 : zp16;
                short8v B = *reinterpret_cast<const short8v*>(src);
                if (nt == 0) acc0 = __builtin_amdgcn_mfma_f32_16x16x32_bf16(A, B, acc0, 0, 0, 0);
                if (nt == 1) acc1 = __builtin_amdgcn_mfma_f32_16x16x32_bf16(A, B, acc1, 0, 0, 0);
                if (nt == 2) acc2 = __builtin_amdgcn_mfma_f32_16x16x32_bf16(A, B, acc2, 0, 0, 0);
                if (nt == 3) acc3 = __builtin_amdgcn_mfma_f32_16x16x32_bf16(A, B, acc3, 0, 0, 0);
            }
        }
    }

    if (kg < 2) {
        #pragma unroll
        for (int nt = 0; nt < 4; ++nt) {
            const f32x4& A = (nt==0) ? acc0 : (nt==1) ? acc1 : (nt==2) ? acc2 : acc3;
            int px = w0 + nt*16 + col;
            short4 pk;
            short* pkp = (short*)&pk;
            #pragma unroll
            for (int r = 0; r < 4; ++r) {
                float v = fmaxf(A[r] + bias[kg*4 + r], 0.f);
                bf16 hb = __float2bfloat16(v);
                pkp[r] = *reinterpret_cast<short*>(&hb);
            }
            *reinterpret_cast<short4*>(c2o + (((size_t)b*HH + h)*WW + px)*8 + kg*4) = pk;
        }
    }
}

// ---------------------------------------------------------------------------
// conv3m: 8->2 ch, 5x5, pad 2, no activation, via mfma_f32_16x16x32_bf16.
__global__ __launch_bounds__(256) void k_conv3m(const short* __restrict__ c2o,
        const short* __restrict__ a3pack, const float* __restrict__ bias,
        float* __restrict__ c3o, const short* __restrict__ zp16) {
    const int tid = threadIdx.x;
    const int l   = tid & 63;
    const int wid = tid >> 6;
    const int h   = blockIdx.y;
    const int b   = blockIdx.z;
    const int w0  = blockIdx.x*256 + wid*64;
    const int col = l & 15;
    const int kg  = l >> 4;           // tap within group

    f32x4 acc0 = {0.f,0.f,0.f,0.f};
    f32x4 acc1 = {0.f,0.f,0.f,0.f};
    f32x4 acc2 = {0.f,0.f,0.f,0.f};
    f32x4 acc3 = {0.f,0.f,0.f,0.f};

    #pragma unroll
    for (int grp = 0; grp < 7; ++grp) {
        int tap = grp*4 + kg;
        int ky = tap / 5, kx = tap - ky*5;
        int gh = h + ky - 2;
        bool tv = (tap < 25) && ((unsigned)gh < (unsigned)HH);
        const short* rowb = c2o + ((size_t)b*HH + (tv ? gh : 0))*WW*8;
        short8v A = *reinterpret_cast<const short8v*>(
            a3pack + ((size_t)grp*64 + l)*8);
        #pragma unroll
        for (int nt = 0; nt < 4; ++nt) {
            int gw = w0 + nt*16 + col + kx - 2;
            const short* src = (tv && (unsigned)gw < (unsigned)WW)
                ? rowb + (size_t)gw*8 : zp16;
            short8v B = *reinterpret_cast<const short8v*>(src);
            if (nt == 0) acc0 = __builtin_amdgcn_mfma_f32_16x16x32_bf16(A, B, acc0, 0, 0, 0);
            if (nt == 1) acc1 = __builtin_amdgcn_mfma_f32_16x16x32_bf16(A, B, acc1, 0, 0, 0);
            if (nt == 2) acc2 = __builtin_amdgcn_mfma_f32_16x16x32_bf16(A, B, acc2, 0, 0, 0);
            if (nt == 3) acc3 = __builtin_amdgcn_mfma_f32_16x16x32_bf16(A, B, acc3, 0, 0, 0);
        }
    }

    if (kg == 0) {
        #pragma unroll
        for (int nt = 0; nt < 4; ++nt) {
            const f32x4& A = (nt==0) ? acc0 : (nt==1) ? acc1 : (nt==2) ? acc2 : acc3;
            int px = w0 + nt*16 + col;
            c3o[((size_t)b*2 + 0)*NPIX + h*WW + px] = A[0] + bias[0];
            c3o[((size_t)b*2 + 1)*NPIX + h*WW + px] = A[1] + bias[1];
        }
    }
}

// ---------------------------------------------------------------------------
__device__ __forceinline__ int refl(int i, int n) {
    if (i < 0) i = -i;
    if (i >= n) i = 2*n - 2 - i;
    return i;
}

// Joint bilateral blur + FUSED per-block u/v min-max partial reduction
// (grid = 2160 full blocks, no inactive lanes -> reduction is exact).
__global__ __launch_bounds__(256) void k_bilat(const float* __restrict__ c3,
        const float* __restrict__ x, float* __restrict__ outb,
        float4* __restrict__ partial) {
    int idx = blockIdx.x * blockDim.x + threadIdx.x;
    int b = idx / NPIX;
    int p = idx - b*NPIX;
    int h = p / WW, w = p - h*WW;
    const float* xb = x + (size_t)b*NPIX;
    const float* f0 = c3 + (size_t)b*2*NPIX;
    const float* f1 = f0 + NPIX;

    float e1 = expf(-1.0f/4.5f), e2 = expf(-4.0f/4.5f);
    float sden = 1.0f + 2.f*e1 + 2.f*e2;
    float g1v[5] = { e2/sden, e1/sden, 1.0f/sden, e1/sden, e2/sden };

    float g = xb[p];
    float num0 = 0.f, num1 = 0.f, den = 0.f;
    #pragma unroll
    for (int dy = 0; dy < 5; ++dy) {
        int hh = refl(h + dy - 2, HH);
        #pragma unroll
        for (int dx = 0; dx < 5; ++dx) {
            int wc = refl(w + dx - 2, WW);
            float gs = xb[hh*WW + wc];
            float d = gs - g;
            float k = g1v[dy] * g1v[dx] * expf(-200.0f * d * d);
            num0 += f0[hh*WW + wc] * k;
            num1 += f1[hh*WW + wc] * k;
            den  += k;
        }
    }
    float invd = 1.0f / den;
    float u = num0 * invd;
    float v = num1 * invd;
    outb[(size_t)b*2*NPIX + p]        = u;
    outb[(size_t)b*2*NPIX + NPIX + p] = v;

    float umin = u, umax = u, vmin = v, vmax = v;
    #pragma unroll
    for (int off = 32; off > 0; off >>= 1) {
        umin = fminf(umin, __shfl_down(umin, off));
        umax = fmaxf(umax, __shfl_down(umax, off));
        vmin = fminf(vmin, __shfl_down(vmin, off));
        vmax = fmaxf(vmax, __shfl_down(vmax, off));
    }
    __shared__ float4 sm[4];
    int lane = threadIdx.x & 63, wvid = threadIdx.x >> 6;
    if (lane == 0) sm[wvid] = make_float4(umin, umax, vmin, vmax);
    __syncthreads();
    if (threadIdx.x == 0) {
        float4 r = sm[0];
        #pragma unroll
        for (int k = 1; k < 4; ++k) {
            r.x = fminf(r.x, sm[k].x); r.y = fmaxf(r.y, sm[k].y);
            r.z = fminf(r.z, sm[k].z); r.w = fmaxf(r.w, sm[k].w);
        }
        partial[blockIdx.x] = r;
    }
}

// ---------------------------------------------------------------------------
__global__ void k_minmax2(const float4* __restrict__ partial, float* __restrict__ sc) {
    float umin = 3.0e38f, umax = -3.0e38f, vmin = 3.0e38f, vmax = -3.0e38f;
    for (int i = threadIdx.x; i < NBLK_BILAT; i += 256) {
        float4 p = partial[i];
        umin = fminf(umin, p.x); umax = fmaxf(umax, p.y);
        vmin = fminf(vmin, p.z); vmax = fmaxf(vmax, p.w);
    }
    #pragma unroll
    for (int off = 32; off > 0; off >>= 1) {
        umin = fminf(umin, __shfl_down(umin, off));
        umax = fmaxf(umax, __shfl_down(umax, off));
        vmin = fminf(vmin, __shfl_down(vmin, off));
        vmax = fmaxf(vmax, __shfl_down(vmax, off));
    }
    __shared__ float4 sm[4];
    int lane = threadIdx.x & 63, wvid = threadIdx.x >> 6;
    if (lane == 0) sm[wvid] = make_float4(umin, umax, vmin, vmax);
    __syncthreads();
    if (threadIdx.x == 0) {
        float4 r = sm[0];
        #pragma unroll
        for (int k = 1; k < 4; ++k) {
            r.x = fminf(r.x, sm[k].x); r.y = fmaxf(r.y, sm[k].y);
            r.z = fminf(r.z, sm[k].z); r.w = fmaxf(r.w, sm[k].w);
        }
        sc[0] = r.x; sc[1] = r.y; sc[2] = r.z; sc[3] = r.w;
    }
}

__global__ void k_final(const float* __restrict__ blur, const float* __restrict__ x,
                        const float* __restrict__ sc, float* __restrict__ out) {
    int idx = blockIdx.x * blockDim.x + threadIdx.x;
    if (idx >= BB*NPIX) return;
    int b = idx / NPIX;
    int p = idx - b*NPIX;
    float umin = sc[0], umax = sc[1], vmin = sc[2], vmax = sc[3];
    float u = blur[(size_t)b*2*NPIX + p];
    float v = blur[(size_t)b*2*NPIX + NPIX + p];
    u = fminf(fmaxf((u - umin) / (umax - umin + 1e-6f), 0.f), 1.f) * 0.872f - 0.436f;
    v = fminf(fmaxf((v - vmin) / (vmax - vmin + 1e-6f), 0.f), 1.f) * 1.23f  - 0.615f;
    float y = x[(size_t)b*NPIX + p];
    out[(size_t)(b*3+0)*NPIX + p] = y + 1.14f*v;
    out[(size_t)(b*3+1)*NPIX + p] = y - 0.396f*u - 0.581f*v;
    out[(size_t)(b*3+2)*NPIX + p] = y + 2.029f*u;
}

// ---------------------------------------------------------------------------
extern "C" void kernel_launch(void* const* d_in, const int* in_sizes, int n_in,
                              void* d_out, int out_size, void* d_ws, size_t ws_size,
                              hipStream_t stream) {
    const float* x  = (const float*)d_in[0];
    const float* w1 = (const float*)d_in[1];
    const float* b1 = (const float*)d_in[2];
    const float* w2 = (const float*)d_in[3];
    const float* b2 = (const float*)d_in[4];
    const float* w3 = (const float*)d_in[5];
    const float* b3 = (const float*)d_in[6];
    float* out = (float*)d_out;
    char* ws = (char*)d_ws;

    const size_t POOLED_OFF = 0;                      // 17,794,944
    const size_t X_OFF      = 17795072;
    const size_t Y_OFF      = X_OFF + 141557760;      // c1o bf16: 35,389,440
    const size_t AP_OFF     = Y_OFF + 35389440;       // apack bf16: 204,800
    const size_t A2_OFF     = AP_OFF + 204800;        // a2pack: 9,216
    const size_t A3_OFF     = A2_OFF + 9216;          // a3pack: 7,168
    const size_t PART_OFF   = A3_OFF + 7168;          // 2160 * 16 = 34,560
    const size_t SC_OFF     = PART_OFF + 34560;       // 16
    const size_t ZP_OFF     = SC_OFF + 256;           // 4,096 zero page

    float*  pooled = (float*)(ws + POOLED_OFF);
    short*  f2     = (short*)(ws + X_OFF);
    short*  c2o    = (short*)(ws + X_OFF);
    float*  c3o    = (float*)(ws + X_OFF + 24000000);
    float*  blur   = (float*)(ws + X_OFF + 32000000);
    short*  c1o    = (short*)(ws + Y_OFF);
    short*  apack  = (short*)(ws + AP_OFF);
    short*  a2p    = (short*)(ws + A2_OFF);
    short*  a3p    = (short*)(ws + A3_OFF);
    float4* part   = (float4*)(ws + PART_OFF);
    float*  sc     = (float*)(ws + SC_OFF);
    float*  zp     = (float*)(ws + ZP_OFF);

    k_wprep<<<512, 256, 0, stream>>>(w1, w2, w3, apack, a2p, a3p, zp);

    dim3 pg((WP + 15)/16, (HP + 15)/16, BB);   // 33 x 17 x 4
    k_pool<<<pg, 256, 0, stream>>>(x, pooled);

    dim3 fg(WW/16, (HH + 15)/16, BB);          // 32 x 17 x 4
    k_feat<<<fg, 256, 0, stream>>>(pooled, f2);

    k_conv1<<<1088, 256, 0, stream>>>(f2, apack, b1, c1o, (const short*)zp);

    dim3 c2g(WW/256, HH, BB);                  // 2 x 270 x 4
    k_conv2m<<<c2g, 256, 0, stream>>>(c1o, a2p, b2, c2o, (const short*)zp);
    k_conv3m<<<c2g, 256, 0, stream>>>(c2o, a3p, b3, c3o, (const short*)zp);

    k_bilat<<<NBLK_BILAT, 256, 0, stream>>>(c3o, x, blur, part);
    k_minmax2<<<1, 256, 0, stream>>>(part, sc);
    k_final<<<(BB*NPIX + 255)/256, 256, 0, stream>>>(blur, x, sc, out);
}

// Round 20
// 268.540 us; speedup vs baseline: 1.0667x; 1.0667x over previous
//
#include <hip/hip_runtime.h>
#include <hip/hip_bf16.h>

typedef __hip_bfloat16 bf16;
typedef __attribute__((ext_vector_type(8))) short short8v;
typedef __attribute__((ext_vector_type(4))) float f32x4;
typedef __attribute__((ext_vector_type(16))) float f32x16;

#define HH 270
#define WW 512
#define BB 4
#define HP 271
#define WP 513
#define NPIX (HH*WW)      // 138240
#define NPOOL (HP*WP)     // 139023
#define TWO_PI 6.28318530717958647692f
#define PLANE ((size_t)BB*NPIX*16)   // shorts per 16-ch f2 plane
#define NBLK_BILAT ((BB*NPIX)/256)   // 2160, exact

// ---------------------------------------------------------------------------
// Weight prep + zero-page init. (unchanged from R19)
__global__ void k_wprep(const float* __restrict__ w1, const float* __restrict__ w2,
                        const float* __restrict__ w3, short* __restrict__ apack,
                        short* __restrict__ a2pack, short* __restrict__ a3pack,
                        float* __restrict__ zp) {
    int stride = gridDim.x * blockDim.x;
    int t0 = blockIdx.x * blockDim.x + threadIdx.x;
    for (int i = t0; i < 1024; i += stride) zp[i] = 0.f;
    for (int i = t0; i < 8*25*64*8; i += stride) {
        int idx = i;
        int j    = idx & 7;  idx >>= 3;
        int lane = idx & 63; idx >>= 6;
        int t    = idx % 25;
        int ck   = idx / 25;
        int o = lane & 31;
        int c = ck*16 + (lane >> 5)*8 + j;
        float v = w1[o*3200 + c*25 + t];
        bf16 h = __float2bfloat16(v);
        apack[i] = *reinterpret_cast<short*>(&h);
    }
    for (int i = t0; i < 9*64*8; i += stride) {
        int j = i & 7; int l = (i >> 3) & 63; int tap = i >> 9;
        int o = l & 15; int cin = (l >> 4)*8 + j;
        float v = (o < 8) ? w2[o*288 + cin*9 + tap] : 0.f;
        bf16 h = __float2bfloat16(v);
        a2pack[i] = *reinterpret_cast<short*>(&h);
    }
    for (int i = t0; i < 7*64*8; i += stride) {
        int j = i & 7; int l = (i >> 3) & 63; int grp = i >> 9;
        int o = l & 15; int tap = grp*4 + (l >> 4);
        float v = (o < 2 && tap < 25) ? w3[o*200 + j*25 + tap] : 0.f;
        bf16 h = __float2bfloat16(v);
        a3pack[i] = *reinterpret_cast<short*>(&h);
    }
}

// ---------------------------------------------------------------------------
// FUSED pool+feat (R20): per 16x16-output block, build the 22x22 per-pixel
// orientation histogram in LDS (grad/atan2/soft-bin once per pixel), window-
// sum it into the 19x19 pooled tile T (replacing k_pool + its 43 MB HBM
// round-trip), then the 2-pass SIFT normalize. Output: 8 planes of 16 ch,
// f2[ck][b][h][w][16] bf16, 8 x 32 B bursts/px. LDS 27 KB.
__global__ __launch_bounds__(256) void k_poolfeat(const float* __restrict__ x,
                                                  short* __restrict__ f2) {
    __shared__ float hist[8][22][22];   // 15,488 B; input rows h0-3..h0+18
    __shared__ float T[8][19][19];      // 11,552 B; pooled rows h0-1..h0+17
    const int tx = threadIdx.x & 15, ty = threadIdx.x >> 4;
    const int w0 = blockIdx.x * 16, h0 = blockIdx.y * 16, b = blockIdx.z;
    const float* xb = x + (size_t)b * NPIX;

    for (int i = threadIdx.x; i < 8*22*22; i += 256) ((float*)hist)[i] = 0.f;
    __syncthreads();

    // Per-pixel gradient/orientation histogram over the 22x22 halo region.
    for (int i = threadIdx.x; i < 484; i += 256) {
        int lh = i / 22, lw = i - lh*22;
        int hh = h0 + lh - 3, ww = w0 + lw - 3;
        if (hh >= 0 && hh < HH && ww >= 0 && ww < WW) {
            float gx = xb[hh*WW + (ww+1 < WW ? ww+1 : WW-1)] - xb[hh*WW + (ww-1 >= 0 ? ww-1 : 0)];
            float gy = xb[(hh+1 < HH ? hh+1 : HH-1)*WW + ww] - xb[(hh-1 >= 0 ? hh-1 : 0)*WW + ww];
            float mag  = sqrtf(gx*gx + gy*gy + 1e-10f);
            float ori  = atan2f(gy, gx + 1e-10f) + TWO_PI;
            float obig = ori * (8.0f / TWO_PI);
            float b0f  = floorf(obig);
            float wo1  = obig - b0f;
            int ib0 = ((int)b0f) & 7;
            int ib1 = (ib0 + 1) & 7;
            hist[ib0][lh][lw] += (1.0f - wo1) * mag;
            hist[ib1][lh][lw] += wo1 * mag;
        }
    }
    __syncthreads();

    // Pooled tile: T[c][lh][lw] = mean of 4x4 hist window (was k_pool).
    // pooled(ph,pw), ph = h0+lh-1: input rows ph+di-2 = hist rows lh+di.
    for (int idx = threadIdx.x; idx < 361; idx += 256) {
        int lh = idx / 19, lw = idx - lh*19;
        int ph = h0 + lh - 1, pw = w0 + lw - 1;
        bool ok = (ph >= 0 && ph < HP && pw >= 0 && pw < WP);
        float a[8];
        #pragma unroll
        for (int c = 0; c < 8; ++c) a[c] = 0.f;
        if (ok) {
            #pragma unroll
            for (int di = 0; di < 4; ++di)
                #pragma unroll
                for (int dj = 0; dj < 4; ++dj) {
                    #pragma unroll
                    for (int c = 0; c < 8; ++c)
                        a[c] += hist[c][lh+di][lw+dj];
                }
        }
        const float s = 1.0f/16.0f;
        #pragma unroll
        for (int c = 0; c < 8; ++c) T[c][lh][lw] = a[c]*s;
    }
    __syncthreads();

    // Pass 1: sum of squares.
    float s2 = 0.f;
    #pragma unroll
    for (int c = 0; c < 8; ++c)
        #pragma unroll
        for (int i = 0; i < 4; ++i)
            #pragma unroll
            for (int j = 0; j < 4; ++j) {
                float u = T[c][ty+i][tx+j];
                s2 += u*u;
            }
    float inv1 = 1.0f / fmaxf(sqrtf(s2), 1e-12f);

    // Pass 2: clip, accumulate sv1/sv2, pack vclip bf16 into registers.
    int outv[64];
    float sv2 = 0.f, sv1 = 0.f;
    #pragma unroll
    for (int c = 0; c < 8; ++c)
        #pragma unroll
        for (int i = 0; i < 4; ++i)
            #pragma unroll
            for (int jj = 0; jj < 2; ++jj) {
                float u0 = T[c][ty+i][tx+jj*2];
                float u1 = T[c][ty+i][tx+jj*2+1];
                float v0 = fminf(u0*inv1, 0.2f);
                float v1 = fminf(u1*inv1, 0.2f);
                sv2 += v0*v0 + v1*v1;
                sv1 += v0 + v1;
                bf16 hb0 = __float2bfloat16(v0);
                bf16 hb1 = __float2bfloat16(v1);
                unsigned lo = *reinterpret_cast<unsigned short*>(&hb0);
                unsigned hi = *reinterpret_cast<unsigned short*>(&hb1);
                outv[c*8 + i*2 + jj] = (int)(lo | (hi << 16));
            }
    float inv2  = 1.0f / fmaxf(sqrtf(sv2), 1e-12f);
    float invl1 = 1.0f / fmaxf(sv1 * inv2, 1e-12f);
    float scale = inv2 * invl1;       // fo = sqrt(vclip*scale + 1e-10)

    // Pass 3: register-only finalize.
    #pragma unroll
    for (int q = 0; q < 64; ++q) {
        unsigned pk = (unsigned)outv[q];
        unsigned u0 = (pk & 0xFFFFu) << 16;
        unsigned u1 = pk & 0xFFFF0000u;
        float v0 = *reinterpret_cast<float*>(&u0);
        float v1 = *reinterpret_cast<float*>(&u1);
        float fo0 = sqrtf(v0*scale + 1e-10f);
        float fo1 = sqrtf(v1*scale + 1e-10f);
        bf16 hb0 = __float2bfloat16(fo0);
        bf16 hb1 = __float2bfloat16(fo1);
        unsigned lo = *reinterpret_cast<unsigned short*>(&hb0);
        unsigned hi = *reinterpret_cast<unsigned short*>(&hb1);
        outv[q] = (int)(lo | (hi << 16));
    }

    int h = h0 + ty, w = w0 + tx;
    if (h < HH) {
        const size_t pix = (size_t)b*NPIX + h*WW + w;
        #pragma unroll
        for (int ck = 0; ck < 8; ++ck) {
            int4* fb = reinterpret_cast<int4*>(f2 + (size_t)ck*PLANE + pix*16);
            int4 v0, v1;
            v0.x = outv[ck*8+0]; v0.y = outv[ck*8+1]; v0.z = outv[ck*8+2]; v0.w = outv[ck*8+3];
            v1.x = outv[ck*8+4]; v1.y = outv[ck*8+5]; v1.z = outv[ck*8+6]; v1.w = outv[ck*8+7];
            fb[0] = v0; fb[1] = v1;
        }
    }
}

// ---------------------------------------------------------------------------
// conv1 v10 (best measured, 132 us): per-wave private double-buffered LDS
// staging, ZERO barriers, counted vmcnt(9). 2 blocks/CU.
__global__ __launch_bounds__(256) void k_conv1(const short* __restrict__ f2,
        const short* __restrict__ apack, const float* __restrict__ bias,
        short* __restrict__ c1o, const short* __restrict__ zp16) {
    __shared__ short S[4][2][4608];   // per wave: 2 bufs x 9216 B
    const int tid = threadIdx.x;
    const int l   = tid & 63;
    const int wid = tid >> 6;
    const int n      = blockIdx.x;
    const int xcd    = n & 7;
    const int t_     = n >> 3;
    const int within = t_ & 7;
    const int g      = (t_ >> 3)*8 + xcd;
    const int b      = g / 34;
    const int ypair  = g - b*34;
    const int h0     = (ypair*2 + (within >> 2)) * 4;
    const int w0     = (within & 3) * 128;
    const int c32 = l & 31;
    const int ksel = l >> 5;
    const int gw0 = w0 + wid*32 - 2;

    short* Sw0 = &S[wid][0][0];
    short* Sw1 = &S[wid][1][0];

    f32x16 acc0 = {0.f};
    f32x16 acc1 = {0.f};
    f32x16 acc2 = {0.f};
    f32x16 acc3 = {0.f};

    auto STAGE = [&](int ck, short* dstbase) {
        const short* plane = f2 + (size_t)ck*PLANE;
        #pragma unroll
        for (int j = 0; j < 9; ++j) {
            int s  = j*64 + l;
            int pr = s / 72;
            int rem = s - pr*72;
            int px = rem >> 1;
            int half = rem & 1;
            int gh = h0 + pr - 2;
            int gw = gw0 + px;
            const short* src = ((unsigned)gh < (unsigned)HH && (unsigned)gw < (unsigned)WW)
                ? plane + (((size_t)b*HH + gh)*WW + gw)*16 + half*8
                : zp16;
            __builtin_amdgcn_global_load_lds(
                (const __attribute__((address_space(1))) void*)src,
                (__attribute__((address_space(3))) void*)(dstbase + j*512), 16, 0, 0);
        }
    };

    STAGE(0, Sw0);

    for (int ck = 0; ck < 8; ++ck) {
        short* cur = (ck & 1) ? Sw1 : Sw0;
        short* nxt = (ck & 1) ? Sw0 : Sw1;
        if (ck < 7) STAGE(ck + 1, nxt);
        asm volatile("s_waitcnt vmcnt(9)" ::: "memory");

        #pragma unroll
        for (int kx = 0; kx < 5; ++kx) {
            const int px = c32 + kx;
            const short* bp = cur + (size_t)px*16 + (size_t)ksel*8;
            short8v Bf[8];
            #pragma unroll
            for (int pr = 0; pr < 8; ++pr)
                Bf[pr] = *reinterpret_cast<const short8v*>(bp + pr*576);
            #pragma unroll
            for (int ky = 0; ky < 5; ++ky) {
                const short* ap = apack + ((size_t)(ck*25 + ky*5 + kx)*64 + l)*8;
                short8v A = *reinterpret_cast<const short8v*>(ap);
                acc0 = __builtin_amdgcn_mfma_f32_32x32x16_bf16(A, Bf[ky+0], acc0, 0, 0, 0);
                acc1 = __builtin_amdgcn_mfma_f32_32x32x16_bf16(A, Bf[ky+1], acc1, 0, 0, 0);
                acc2 = __builtin_amdgcn_mfma_f32_32x32x16_bf16(A, Bf[ky+2], acc2, 0, 0, 0);
                acc3 = __builtin_amdgcn_mfma_f32_32x32x16_bf16(A, Bf[ky+3], acc3, 0, 0, 0);
            }
        }
        asm volatile("s_waitcnt lgkmcnt(0)" ::: "memory");
    }

    const int px = w0 + wid*32 + c32;
    #pragma unroll
    for (int r = 0; r < 4; ++r) {
        int h = h0 + r;
        if (h < HH) {
            const f32x16& A = (r==0) ? acc0 : (r==1) ? acc1 : (r==2) ? acc2 : acc3;
            const size_t rowbase = ((size_t)b*HH + h)*4;
            #pragma unroll
            for (int q = 0; q < 4; ++q) {
                short4 pk;
                short* pkp = (short*)&pk;
                #pragma unroll
                for (int j = 0; j < 4; ++j) {
                    float v = fmaxf(A[q*4 + j] + bias[q*8 + 4*ksel + j], 0.f);
                    bf16 hb = __float2bfloat16(v);
                    pkp[j] = *reinterpret_cast<short*>(&hb);
                }
                *reinterpret_cast<short4*>(c1o + ((rowbase + q)*WW + px)*8 + ksel*4) = pk;
            }
        }
    }
}

// ---------------------------------------------------------------------------
// conv2m: 32->8 ch, 3x3, pad 1, ReLU via mfma_f32_16x16x32_bf16.
__global__ __launch_bounds__(256) void k_conv2m(const short* __restrict__ c1o,
        const short* __restrict__ a2pack, const float* __restrict__ bias,
        short* __restrict__ c2o, const short* __restrict__ zp16) {
    const int tid = threadIdx.x;
    const int l   = tid & 63;
    const int wid = tid >> 6;
    const int h   = blockIdx.y;
    const int b   = blockIdx.z;
    const int w0  = blockIdx.x*256 + wid*64;
    const int col = l & 15;
    const int kg  = l >> 4;           // k-group == c1o quad

    f32x4 acc0 = {0.f,0.f,0.f,0.f};
    f32x4 acc1 = {0.f,0.f,0.f,0.f};
    f32x4 acc2 = {0.f,0.f,0.f,0.f};
    f32x4 acc3 = {0.f,0.f,0.f,0.f};

    #pragma unroll
    for (int ky = 0; ky < 3; ++ky) {
        int gh = h + ky - 1;
        bool rv = ((unsigned)gh < (unsigned)HH);
        const short* rowb = c1o + (((size_t)b*HH + (rv ? gh : 0))*4 + kg)*WW*8;
        #pragma unroll
        for (int kx = 0; kx < 3; ++kx) {
            short8v A = *reinterpret_cast<const short8v*>(
                a2pack + ((size_t)(ky*3 + kx)*64 + l)*8);
            #pragma unroll
            for (int nt = 0; nt < 4; ++nt) {
                int gw = w0 + nt*16 + col + kx - 1;
                const short* src = (rv && (unsigned)gw < (unsigned)WW)
                    ? rowb + (size_t)gw*8 : zp16;
                short8v B = *reinterpret_cast<const short8v*>(src);
                if (nt == 0) acc0 = __builtin_amdgcn_mfma_f32_16x16x32_bf16(A, B, acc0, 0, 0, 0);
                if (nt == 1) acc1 = __builtin_amdgcn_mfma_f32_16x16x32_bf16(A, B, acc1, 0, 0, 0);
                if (nt == 2) acc2 = __builtin_amdgcn_mfma_f32_16x16x32_bf16(A, B, acc2, 0, 0, 0);
                if (nt == 3) acc3 = __builtin_amdgcn_mfma_f32_16x16x32_bf16(A, B, acc3, 0, 0, 0);
            }
        }
    }

    if (kg < 2) {
        #pragma unroll
        for (int nt = 0; nt < 4; ++nt) {
            const f32x4& A = (nt==0) ? acc0 : (nt==1) ? acc1 : (nt==2) ? acc2 : acc3;
            int px = w0 + nt*16 + col;
            short4 pk;
            short* pkp = (short*)&pk;
            #pragma unroll
            for (int r = 0; r < 4; ++r) {
                float v = fmaxf(A[r] + bias[kg*4 + r], 0.f);
                bf16 hb = __float2bfloat16(v);
                pkp[r] = *reinterpret_cast<short*>(&hb);
            }
            *reinterpret_cast<short4*>(c2o + (((size_t)b*HH + h)*WW + px)*8 + kg*4) = pk;
        }
    }
}

// ---------------------------------------------------------------------------
// conv3m: 8->2 ch, 5x5, pad 2, no activation, via mfma_f32_16x16x32_bf16.
__global__ __launch_bounds__(256) void k_conv3m(const short* __restrict__ c2o,
        const short* __restrict__ a3pack, const float* __restrict__ bias,
        float* __restrict__ c3o, const short* __restrict__ zp16) {
    const int tid = threadIdx.x;
    const int l   = tid & 63;
    const int wid = tid >> 6;
    const int h   = blockIdx.y;
    const int b   = blockIdx.z;
    const int w0  = blockIdx.x*256 + wid*64;
    const int col = l & 15;
    const int kg  = l >> 4;           // tap within group

    f32x4 acc0 = {0.f,0.f,0.f,0.f};
    f32x4 acc1 = {0.f,0.f,0.f,0.f};
    f32x4 acc2 = {0.f,0.f,0.f,0.f};
    f32x4 acc3 = {0.f,0.f,0.f,0.f};

    #pragma unroll
    for (int grp = 0; grp < 7; ++grp) {
        int tap = grp*4 + kg;
        int ky = tap / 5, kx = tap - ky*5;
        int gh = h + ky - 2;
        bool tv = (tap < 25) && ((unsigned)gh < (unsigned)HH);
        const short* rowb = c2o + ((size_t)b*HH + (tv ? gh : 0))*WW*8;
        short8v A = *reinterpret_cast<const short8v*>(
            a3pack + ((size_t)grp*64 + l)*8);
        #pragma unroll
        for (int nt = 0; nt < 4; ++nt) {
            int gw = w0 + nt*16 + col + kx - 2;
            const short* src = (tv && (unsigned)gw < (unsigned)WW)
                ? rowb + (size_t)gw*8 : zp16;
            short8v B = *reinterpret_cast<const short8v*>(src);
            if (nt == 0) acc0 = __builtin_amdgcn_mfma_f32_16x16x32_bf16(A, B, acc0, 0, 0, 0);
            if (nt == 1) acc1 = __builtin_amdgcn_mfma_f32_16x16x32_bf16(A, B, acc1, 0, 0, 0);
            if (nt == 2) acc2 = __builtin_amdgcn_mfma_f32_16x16x32_bf16(A, B, acc2, 0, 0, 0);
            if (nt == 3) acc3 = __builtin_amdgcn_mfma_f32_16x16x32_bf16(A, B, acc3, 0, 0, 0);
        }
    }

    if (kg == 0) {
        #pragma unroll
        for (int nt = 0; nt < 4; ++nt) {
            const f32x4& A = (nt==0) ? acc0 : (nt==1) ? acc1 : (nt==2) ? acc2 : acc3;
            int px = w0 + nt*16 + col;
            c3o[((size_t)b*2 + 0)*NPIX + h*WW + px] = A[0] + bias[0];
            c3o[((size_t)b*2 + 1)*NPIX + h*WW + px] = A[1] + bias[1];
        }
    }
}

// ---------------------------------------------------------------------------
__device__ __forceinline__ int refl(int i, int n) {
    if (i < 0) i = -i;
    if (i >= n) i = 2*n - 2 - i;
    return i;
}

// Joint bilateral blur + FUSED per-block u/v min-max partial reduction.
__global__ __launch_bounds__(256) void k_bilat(const float* __restrict__ c3,
        const float* __restrict__ x, float* __restrict__ outb,
        float4* __restrict__ partial) {
    int idx = blockIdx.x * blockDim.x + threadIdx.x;
    int b = idx / NPIX;
    int p = idx - b*NPIX;
    int h = p / WW, w = p - h*WW;
    const float* xb = x + (size_t)b*NPIX;
    const float* f0 = c3 + (size_t)b*2*NPIX;
    const float* f1 = f0 + NPIX;

    float e1 = expf(-1.0f/4.5f), e2 = expf(-4.0f/4.5f);
    float sden = 1.0f + 2.f*e1 + 2.f*e2;
    float g1v[5] = { e2/sden, e1/sden, 1.0f/sden, e1/sden, e2/sden };

    float g = xb[p];
    float num0 = 0.f, num1 = 0.f, den = 0.f;
    #pragma unroll
    for (int dy = 0; dy < 5; ++dy) {
        int hh = refl(h + dy - 2, HH);
        #pragma unroll
        for (int dx = 0; dx < 5; ++dx) {
            int wc = refl(w + dx - 2, WW);
            float gs = xb[hh*WW + wc];
            float d = gs - g;
            float k = g1v[dy] * g1v[dx] * expf(-200.0f * d * d);
            num0 += f0[hh*WW + wc] * k;
            num1 += f1[hh*WW + wc] * k;
            den  += k;
        }
    }
    float invd = 1.0f / den;
    float u = num0 * invd;
    float v = num1 * invd;
    outb[(size_t)b*2*NPIX + p]        = u;
    outb[(size_t)b*2*NPIX + NPIX + p] = v;

    float umin = u, umax = u, vmin = v, vmax = v;
    #pragma unroll
    for (int off = 32; off > 0; off >>= 1) {
        umin = fminf(umin, __shfl_down(umin, off));
        umax = fmaxf(umax, __shfl_down(umax, off));
        vmin = fminf(vmin, __shfl_down(vmin, off));
        vmax = fmaxf(vmax, __shfl_down(vmax, off));
    }
    __shared__ float4 sm[4];
    int lane = threadIdx.x & 63, wvid = threadIdx.x >> 6;
    if (lane == 0) sm[wvid] = make_float4(umin, umax, vmin, vmax);
    __syncthreads();
    if (threadIdx.x == 0) {
        float4 r = sm[0];
        #pragma unroll
        for (int k = 1; k < 4; ++k) {
            r.x = fminf(r.x, sm[k].x); r.y = fmaxf(r.y, sm[k].y);
            r.z = fminf(r.z, sm[k].z); r.w = fmaxf(r.w, sm[k].w);
        }
        partial[blockIdx.x] = r;
    }
}

// ---------------------------------------------------------------------------
__global__ void k_minmax2(const float4* __restrict__ partial, float* __restrict__ sc) {
    float umin = 3.0e38f, umax = -3.0e38f, vmin = 3.0e38f, vmax = -3.0e38f;
    for (int i = threadIdx.x; i < NBLK_BILAT; i += 256) {
        float4 p = partial[i];
        umin = fminf(umin, p.x); umax = fmaxf(umax, p.y);
        vmin = fminf(vmin, p.z); vmax = fmaxf(vmax, p.w);
    }
    #pragma unroll
    for (int off = 32; off > 0; off >>= 1) {
        umin = fminf(umin, __shfl_down(umin, off));
        umax = fmaxf(umax, __shfl_down(umax, off));
        vmin = fminf(vmin, __shfl_down(vmin, off));
        vmax = fmaxf(vmax, __shfl_down(vmax, off));
    }
    __shared__ float4 sm[4];
    int lane = threadIdx.x & 63, wvid = threadIdx.x >> 6;
    if (lane == 0) sm[wvid] = make_float4(umin, umax, vmin, vmax);
    __syncthreads();
    if (threadIdx.x == 0) {
        float4 r = sm[0];
        #pragma unroll
        for (int k = 1; k < 4; ++k) {
            r.x = fminf(r.x, sm[k].x); r.y = fmaxf(r.y, sm[k].y);
            r.z = fminf(r.z, sm[k].z); r.w = fmaxf(r.w, sm[k].w);
        }
        sc[0] = r.x; sc[1] = r.y; sc[2] = r.z; sc[3] = r.w;
    }
}

__global__ void k_final(const float* __restrict__ blur, const float* __restrict__ x,
                        const float* __restrict__ sc, float* __restrict__ out) {
    int idx = blockIdx.x * blockDim.x + threadIdx.x;
    if (idx >= BB*NPIX) return;
    int b = idx / NPIX;
    int p = idx - b*NPIX;
    float umin = sc[0], umax = sc[1], vmin = sc[2], vmax = sc[3];
    float u = blur[(size_t)b*2*NPIX + p];
    float v = blur[(size_t)b*2*NPIX + NPIX + p];
    u = fminf(fmaxf((u - umin) / (umax - umin + 1e-6f), 0.f), 1.f) * 0.872f - 0.436f;
    v = fminf(fmaxf((v - vmin) / (vmax - vmin + 1e-6f), 0.f), 1.f) * 1.23f  - 0.615f;
    float y = x[(size_t)b*NPIX + p];
    out[(size_t)(b*3+0)*NPIX + p] = y + 1.14f*v;
    out[(size_t)(b*3+1)*NPIX + p] = y - 0.396f*u - 0.581f*v;
    out[(size_t)(b*3+2)*NPIX + p] = y + 2.029f*u;
}

// ---------------------------------------------------------------------------
extern "C" void kernel_launch(void* const* d_in, const int* in_sizes, int n_in,
                              void* d_out, int out_size, void* d_ws, size_t ws_size,
                              hipStream_t stream) {
    const float* x  = (const float*)d_in[0];
    const float* w1 = (const float*)d_in[1];
    const float* b1 = (const float*)d_in[2];
    const float* w2 = (const float*)d_in[3];
    const float* b2 = (const float*)d_in[4];
    const float* w3 = (const float*)d_in[5];
    const float* b3 = (const float*)d_in[6];
    float* out = (float*)d_out;
    char* ws = (char*)d_ws;

    const size_t X_OFF      = 17795072;
    const size_t Y_OFF      = X_OFF + 141557760;      // c1o bf16: 35,389,440
    const size_t AP_OFF     = Y_OFF + 35389440;       // apack bf16: 204,800
    const size_t A2_OFF     = AP_OFF + 204800;        // a2pack: 9,216
    const size_t A3_OFF     = A2_OFF + 9216;          // a3pack: 7,168
    const size_t PART_OFF   = A3_OFF + 7168;          // 2160 * 16 = 34,560
    const size_t SC_OFF     = PART_OFF + 34560;       // 16
    const size_t ZP_OFF     = SC_OFF + 256;           // 4,096 zero page

    short*  f2     = (short*)(ws + X_OFF);
    short*  c2o    = (short*)(ws + X_OFF);
    float*  c3o    = (float*)(ws + X_OFF + 24000000);
    float*  blur   = (float*)(ws + X_OFF + 32000000);
    short*  c1o    = (short*)(ws + Y_OFF);
    short*  apack  = (short*)(ws + AP_OFF);
    short*  a2p    = (short*)(ws + A2_OFF);
    short*  a3p    = (short*)(ws + A3_OFF);
    float4* part   = (float4*)(ws + PART_OFF);
    float*  sc     = (float*)(ws + SC_OFF);
    float*  zp     = (float*)(ws + ZP_OFF);

    k_wprep<<<512, 256, 0, stream>>>(w1, w2, w3, apack, a2p, a3p, zp);

    dim3 fg(WW/16, (HH + 15)/16, BB);          // 32 x 17 x 4
    k_poolfeat<<<fg, 256, 0, stream>>>(x, f2);

    k_conv1<<<1088, 256, 0, stream>>>(f2, apack, b1, c1o, (const short*)zp);

    dim3 c2g(WW/256, HH, BB);                  // 2 x 270 x 4
    k_conv2m<<<c2g, 256, 0, stream>>>(c1o, a2p, b2, c2o, (const short*)zp);
    k_conv3m<<<c2g, 256, 0, stream>>>(c2o, a3p, b3, c3o, (const short*)zp);

    k_bilat<<<NBLK_BILAT, 256, 0, stream>>>(c3o, x, blur, part);
    k_minmax2<<<1, 256, 0, stream>>>(part, sc);
    k_final<<<(BB*NPIX + 255)/256, 256, 0, stream>>>(blur, x, sc, out);
}